// Round 14
// baseline (211.679 us; speedup 1.0000x reference)
//
#include <hip/hip_runtime.h>

// Single fused kernel (grid 1024 = b*2+s, 256 thr, 4 blocks/CU):
//   B-frags packed in-kernel from w2 (per-lane, L1-hot).
//   P1 conv1+relu+pool via packed-f32 -> LDS f16 h-tile hsu[4][30][58]
//   P2 conv2+pool+relu via mfma_f32_16x16x32_f16 (strip = one 2x2 patch,
//      A gathered from hsu, 12 ds_read_b32; strip loop unrolled x2);
//      fv -> fsu rows; chunk-reduce via fdot2 -> pfl[392]
//   P3 fc1 partial -> h1p[b][s][64] (global ws)
//   Tail: last-finishing block per b (atomic flag) does relu+fc2+log_softmax.
// flags zeroed via hipMemsetAsync on stream before launch.

#define HSTR 58   // 56 cols + 2 halo cols (u32 units)
#define NROWS 30  // 28 tile h-rows + 2 halo
#define FSTR 33   // fsu row stride in u32 (66 f16) -> conflict-free reduce

typedef _Float16 half2_t __attribute__((ext_vector_type(2)));
typedef _Float16 f16x8 __attribute__((ext_vector_type(8)));
typedef float f32x4 __attribute__((ext_vector_type(4)));
typedef float f32x2 __attribute__((ext_vector_type(2)));

__device__ __forceinline__ unsigned pack_f16(float a, float b) {
  union { half2_t h; unsigned u; } z;
  z.h[0] = (_Float16)a;
  z.h[1] = (_Float16)b;
  return z.u;
}

__device__ __forceinline__ half2_t as_h2(unsigned u) {
  union { unsigned u; half2_t h; } z;
  z.u = u;
  return z.h;
}

__device__ __forceinline__ f16x8 as_f16x8(uint4 u) {
  union { uint4 u; f16x8 f; } z;
  z.u = u;
  return z.f;
}

__device__ __forceinline__ float fdot2_(half2_t a, half2_t b, float c) {
#if __has_builtin(__builtin_amdgcn_fdot2)
  return __builtin_amdgcn_fdot2(a, b, c, false);
#else
  return c + (float)a[0] * (float)b[0] + (float)a[1] * (float)b[1];
#endif
}

__global__ __launch_bounds__(256, 4) void k_fused(
    const float* __restrict__ x, const float* __restrict__ w1,
    const float* __restrict__ b1, const float* __restrict__ w2,
    const float* __restrict__ b2, const float* __restrict__ wp,
    const float* __restrict__ bp, const float* __restrict__ w_fc1,
    const float* __restrict__ b_fc1, const float* __restrict__ w_fc2,
    const float* __restrict__ b_fc2, float* __restrict__ h1p,
    int* __restrict__ flags, float* __restrict__ out) {
  __shared__ __align__(16) unsigned hsu[4 * NROWS * HSTR];  // 27.2 KB
  __shared__ __align__(16) unsigned fsu[49 * FSTR];         // 6.3 KB (f16 rows)
  __shared__ __align__(16) float pfl[392];                  // 1.6 KB
  __shared__ float h1s[64];
  __shared__ float red[11];
  __shared__ int dflag;
  const int tid = threadIdx.x;
  const int b = blockIdx.x >> 1;
  const int s = blockIdx.x & 1;
  const int l = tid & 63;
  const int wv = __builtin_amdgcn_readfirstlane(tid >> 6);  // wave id 0..3
  const float* xb = x + (long)b * 12544;

  // ---- In-kernel B-frag pack (was k_prew): lane (oc=l&15, q=l>>4) ----
  const int q = l >> 4;
  uint4 bu[3];
#pragma unroll
  for (int kk = 0; kk < 3; ++kk) {
    unsigned vbits[4];
#pragma unroll
    for (int i = 0; i < 4; ++i) {
      int k32 = kk * 16 + q * 4 + i;
      unsigned v = 0u;
      if (k32 < 36) {
        int icp = k32 / 9, tap = k32 - icp * 9;
        v = pack_f16(w2[((l & 15) * 8 + 2 * icp) * 9 + tap],
                     w2[((l & 15) * 8 + 2 * icp + 1) * 9 + tap]);
      }
      vbits[i] = v;
    }
    bu[kk] = make_uint4(vbits[0], vbits[1], vbits[2], vbits[3]);
  }

  // Per-thread packed wp pairs for the chunk-reduce (ot = tid&3):
  unsigned wpk[32];
  {
    int ot0 = tid & 3;
#pragma unroll
    for (int i = 0; i < 32; ++i) {
      int l0 = 2 * i, l1 = 2 * i + 1;
      wpk[i] = pack_f16(wp[ot0 * 64 + (l0 & 15) * 4 + (l0 >> 4)],
                        wp[ot0 * 64 + (l1 & 15) * 4 + (l1 >> 4)]);
    }
  }
  const float bpv = bp[tid & 3];

  for (int i = tid; i < 4 * NROWS * HSTR; i += 256) hsu[i] = 0u;
  __syncthreads();

  // ---- P1: conv1(1->8)+bias+relu+maxpool2 (packed f32) -> f16 LDS tile ----
  for (int task = tid; task < 1680; task += 256) {
    int r = task / 56, hc = task % 56;
    int gr = 28 * s - 1 + r;
    if ((unsigned)gr >= 56u) continue;
    float win[4][4];
    int iy0 = 2 * gr - 1, ix0 = 2 * hc - 1;
#pragma unroll
    for (int rr = 0; rr < 4; ++rr) {
      int iy = iy0 + rr;
      bool yok = (unsigned)iy < 112u;
#pragma unroll
      for (int qq = 0; qq < 4; ++qq) {
        int ix = ix0 + qq;
        win[rr][qq] = (yok && (unsigned)ix < 112u) ? xb[iy * 112 + ix] : 0.f;
      }
    }
    float hv[8];
#pragma unroll
    for (int c = 0; c < 8; ++c) {
      f32x2 sA = {0.f, 0.f};  // (s00, s01)
      f32x2 sB = {0.f, 0.f};  // (s10, s11)
#pragma unroll
      for (int ty = 0; ty < 3; ++ty)
#pragma unroll
        for (int tx = 0; tx < 3; ++tx) {
          float wk = w1[c * 9 + ty * 3 + tx];
          f32x2 wkk = {wk, wk};
          f32x2 xa = {win[ty][tx], win[ty][tx + 1]};
          f32x2 xb2 = {win[ty + 1][tx], win[ty + 1][tx + 1]};
          sA = __builtin_elementwise_fma(xa, wkk, sA);
          sB = __builtin_elementwise_fma(xb2, wkk, sB);
        }
      f32x2 sm = __builtin_elementwise_max(sA, sB);
      float m = fmaxf(sm.x, sm.y);
      hv[c] = fmaxf(m + b1[c], 0.f);
    }
#pragma unroll
    for (int cp = 0; cp < 4; ++cp)
      hsu[(cp * NROWS + r) * HSTR + 1 + hc] = pack_f16(hv[2 * cp], hv[2 * cp + 1]);
  }
  __syncthreads();

  // ---- P2: conv2+pool+relu via MFMA; fv -> fsu; chunked patch reduce ----
  {
    int offs[12];
#pragma unroll
    for (int kk = 0; kk < 3; ++kk)
#pragma unroll
      for (int i = 0; i < 4; ++i) {
        int k32 = kk * 16 + q * 4 + i;
        int icp = k32 / 9, tap = k32 - icp * 9;
        int ty = tap / 3, tx = tap - ty * 3;
        offs[kk * 4 + i] = (icp * NROWS + ty) * HSTR + tx;  // junk if k32>=36
      }
    const int yoff = 2 * ((l >> 3) & 1) + ((l >> 1) & 1);  // 2a+dy
    const int xoff = 2 * ((l >> 2) & 1) + (l & 1);         // 2b+dx
    const float b2v = b2[l & 15];
    _Float16* fsh = (_Float16*)fsu;

#pragma unroll 1
    for (int c = 0; c < 2; ++c) {  // chunk: patches c*49 .. c*49+48
#pragma unroll 2
      for (int p_l = wv; p_l < 49; p_l += 4) {
        int p = c * 49 + p_l;
        int py = p / 14, px = p - py * 14;
        int base = (4 * py + yoff) * HSTR + 4 * px + xoff;
        uint4 a0u, a1u, a2u = make_uint4(0u, 0u, 0u, 0u);
        a0u.x = hsu[base + offs[0]];
        a0u.y = hsu[base + offs[1]];
        a0u.z = hsu[base + offs[2]];
        a0u.w = hsu[base + offs[3]];
        a1u.x = hsu[base + offs[4]];
        a1u.y = hsu[base + offs[5]];
        a1u.z = hsu[base + offs[6]];
        a1u.w = hsu[base + offs[7]];
        if (q == 0) {  // only k32 32..35 real in K-step 2
          a2u.x = hsu[base + offs[8]];
          a2u.y = hsu[base + offs[9]];
          a2u.z = hsu[base + offs[10]];
          a2u.w = hsu[base + offs[11]];
        }
        f32x4 acc = {0.f, 0.f, 0.f, 0.f};
        acc = __builtin_amdgcn_mfma_f32_16x16x32_f16(as_f16x8(a0u), as_f16x8(bu[0]), acc, 0, 0, 0);
        acc = __builtin_amdgcn_mfma_f32_16x16x32_f16(as_f16x8(a1u), as_f16x8(bu[1]), acc, 0, 0, 0);
        acc = __builtin_amdgcn_mfma_f32_16x16x32_f16(as_f16x8(a2u), as_f16x8(bu[2]), acc, 0, 0, 0);
        float mx = fmaxf(fmaxf(acc[0], acc[1]), fmaxf(acc[2], acc[3]));
        float fv = fmaxf(mx + b2v, 0.f);  // f[oc=l&15][f-pixel fmem=q of patch p]
        fsh[p_l * (2 * FSTR) + l] = (_Float16)fv;
      }
      __syncthreads();
      // chunk reduce: thread t<196 -> (row=p_l, ot); 32 fdot2 over 64 lanes
      if (tid < 196) {
        int row = tid >> 2, ot = tid & 3;
        int p = c * 49 + row;
        const unsigned* fr = fsu + row * FSTR;
        float acc = 0.f;
#pragma unroll
        for (int i = 0; i < 32; ++i) acc = fdot2_(as_h2(fr[i]), as_h2(wpk[i]), acc);
        pfl[p * 4 + ot] = acc + bpv;
      }
      __syncthreads();
    }
  }

  // ---- P3: fc1 partial over this tile's pf slice [392s, 392s+392) ----
  {
    int j = tid >> 2, q4 = tid & 3;
    const float2* wrow = (const float2*)(w_fc1 + j * 784 + 392 * s + q4 * 98);
    const float2* pv = (const float2*)(pfl + q4 * 98);
    float acc = 0.f;
#pragma unroll 7
    for (int m = 0; m < 49; ++m) {
      float2 wv2 = wrow[m], fv2 = pv[m];
      acc += wv2.x * fv2.x + wv2.y * fv2.y;
    }
    acc += __shfl_down(acc, 2, 4);
    acc += __shfl_down(acc, 1, 4);
    if (q4 == 0) h1p[((long)b * 2 + s) * 64 + j] = acc;
  }
  __syncthreads();

  // ---- Tail: last-finishing block of this b does fc2 + log_softmax ----
  if (tid == 0) {
    __threadfence();                       // release h1p stores
    dflag = atomicAdd(&flags[b], 1);       // device-scope
  }
  __syncthreads();
  if (dflag == 1) {                        // block-uniform branch
    __threadfence();                       // acquire other block's h1p
    if (tid < 64) {
      float v = b_fc1[tid] + h1p[(long)b * 128 + tid] +
                h1p[(long)b * 128 + 64 + tid];
      h1s[tid] = fmaxf(v, 0.f);
    }
    __syncthreads();
    if (tid < 10) {
      float acc = b_fc2[tid];
      const float* wo = w_fc2 + tid * 64;
#pragma unroll
      for (int k = 0; k < 64; ++k) acc += h1s[k] * wo[k];
      red[tid] = acc;
    }
    __syncthreads();
    if (tid == 0) {
      float mx = red[0];
      for (int o = 1; o < 10; ++o) mx = fmaxf(mx, red[o]);
      float se = 0.f;
      for (int o = 0; o < 10; ++o) se += expf(red[o] - mx);
      red[10] = mx + logf(se);
    }
    __syncthreads();
    if (tid < 10) out[b * 10 + tid] = red[tid] - red[10];
  }
}

extern "C" void kernel_launch(void* const* d_in, const int* in_sizes, int n_in,
                              void* d_out, int out_size, void* d_ws, size_t ws_size,
                              hipStream_t stream) {
  const float* x = (const float*)d_in[0];
  const float* w1 = (const float*)d_in[1];
  const float* b1 = (const float*)d_in[2];
  const float* w2 = (const float*)d_in[3];
  const float* b2 = (const float*)d_in[4];
  const float* wp = (const float*)d_in[5];
  const float* bp = (const float*)d_in[6];
  const float* wf1 = (const float*)d_in[7];
  const float* bf1 = (const float*)d_in[8];
  const float* wf2 = (const float*)d_in[9];
  const float* bf2 = (const float*)d_in[10];

  float* h1p = (float*)d_ws;            // [512][2][64] = 65536 floats (256 KB)
  int* flags = (int*)(h1p + 65536);     // [512] completion counters

  hipMemsetAsync(flags, 0, 512 * sizeof(int), stream);
  k_fused<<<dim3(1024), 256, 0, stream>>>(x, w1, b1, w2, b2, wp, bp, wf1, bf1,
                                          wf2, bf2, h1p, flags, (float*)d_out);
}

// Round 15
// 134.228 us; speedup vs baseline: 1.5770x; 1.5770x over previous
//
#include <hip/hip_runtime.h>

// Fused pipeline (R13 structure; B-frags packed in-kernel; NO cross-block sync):
//   k_fused (grid 1024 = b*2+s, 256 thr, 4 blocks/CU):
//     B-frag pack from w2 (per-lane, L1-hot, once per block)
//     P1 conv1+relu+pool via packed-f32 -> LDS f16 h-tile hsu[4][30][58]
//     P2 conv2+pool+relu via mfma_f32_16x16x32_f16 (strip = one 2x2 patch,
//        A gathered from hsu, 12 ds_read_b32; strip loop unrolled x2);
//        fv -> fsu rows; chunk-reduce via fdot2 -> pfl[392]
//     P3 fc1 partial -> h1p[b][s][64] (global ws)
//   k_tail: h1 = relu(sum_s h1p + b_fc1); fc2; log_softmax -> out[512,10]
// R14 lesson: device-scope fence/atomic tail-merge forces L2 writeback/invalidate
// (non-coherent XCD L2s) and serializes the grid — keep the dispatch boundary.

#define HSTR 58   // 56 cols + 2 halo cols (u32 units)
#define NROWS 30  // 28 tile h-rows + 2 halo
#define FSTR 33   // fsu row stride in u32 (66 f16) -> conflict-free reduce

typedef _Float16 half2_t __attribute__((ext_vector_type(2)));
typedef _Float16 f16x8 __attribute__((ext_vector_type(8)));
typedef float f32x4 __attribute__((ext_vector_type(4)));
typedef float f32x2 __attribute__((ext_vector_type(2)));

__device__ __forceinline__ unsigned pack_f16(float a, float b) {
  union { half2_t h; unsigned u; } z;
  z.h[0] = (_Float16)a;
  z.h[1] = (_Float16)b;
  return z.u;
}

__device__ __forceinline__ half2_t as_h2(unsigned u) {
  union { unsigned u; half2_t h; } z;
  z.u = u;
  return z.h;
}

__device__ __forceinline__ f16x8 as_f16x8(uint4 u) {
  union { uint4 u; f16x8 f; } z;
  z.u = u;
  return z.f;
}

__device__ __forceinline__ float fdot2_(half2_t a, half2_t b, float c) {
#if __has_builtin(__builtin_amdgcn_fdot2)
  return __builtin_amdgcn_fdot2(a, b, c, false);
#else
  return c + (float)a[0] * (float)b[0] + (float)a[1] * (float)b[1];
#endif
}

__global__ __launch_bounds__(256, 4) void k_fused(
    const float* __restrict__ x, const float* __restrict__ w1,
    const float* __restrict__ b1, const float* __restrict__ w2,
    const float* __restrict__ b2, const float* __restrict__ wp,
    const float* __restrict__ bp, const float* __restrict__ w_fc1,
    float* __restrict__ h1p) {
  __shared__ __align__(16) unsigned hsu[4 * NROWS * HSTR];  // 27.2 KB
  __shared__ __align__(16) unsigned fsu[49 * FSTR];         // 6.3 KB (f16 rows)
  __shared__ __align__(16) float pfl[392];                  // 1.6 KB
  const int tid = threadIdx.x;
  const int b = blockIdx.x >> 1;
  const int s = blockIdx.x & 1;
  const int l = tid & 63;
  const int wv = __builtin_amdgcn_readfirstlane(tid >> 6);  // wave id 0..3
  const float* xb = x + (long)b * 12544;

  // ---- In-kernel B-frag pack: lane (oc=l&15, q=l>>4) ----
  const int q = l >> 4;
  uint4 bu[3];
#pragma unroll
  for (int kk = 0; kk < 3; ++kk) {
    unsigned vbits[4];
#pragma unroll
    for (int i = 0; i < 4; ++i) {
      int k32 = kk * 16 + q * 4 + i;
      unsigned v = 0u;
      if (k32 < 36) {
        int icp = k32 / 9, tap = k32 - icp * 9;
        v = pack_f16(w2[((l & 15) * 8 + 2 * icp) * 9 + tap],
                     w2[((l & 15) * 8 + 2 * icp + 1) * 9 + tap]);
      }
      vbits[i] = v;
    }
    bu[kk] = make_uint4(vbits[0], vbits[1], vbits[2], vbits[3]);
  }

  // Per-thread packed wp pairs for the chunk-reduce (ot = tid&3):
  unsigned wpk[32];
  {
    int ot0 = tid & 3;
#pragma unroll
    for (int i = 0; i < 32; ++i) {
      int l0 = 2 * i, l1 = 2 * i + 1;
      wpk[i] = pack_f16(wp[ot0 * 64 + (l0 & 15) * 4 + (l0 >> 4)],
                        wp[ot0 * 64 + (l1 & 15) * 4 + (l1 >> 4)]);
    }
  }
  const float bpv = bp[tid & 3];

  for (int i = tid; i < 4 * NROWS * HSTR; i += 256) hsu[i] = 0u;
  __syncthreads();

  // ---- P1: conv1(1->8)+bias+relu+maxpool2 (packed f32) -> f16 LDS tile ----
  for (int task = tid; task < 1680; task += 256) {
    int r = task / 56, hc = task % 56;
    int gr = 28 * s - 1 + r;
    if ((unsigned)gr >= 56u) continue;
    float win[4][4];
    int iy0 = 2 * gr - 1, ix0 = 2 * hc - 1;
#pragma unroll
    for (int rr = 0; rr < 4; ++rr) {
      int iy = iy0 + rr;
      bool yok = (unsigned)iy < 112u;
#pragma unroll
      for (int qq = 0; qq < 4; ++qq) {
        int ix = ix0 + qq;
        win[rr][qq] = (yok && (unsigned)ix < 112u) ? xb[iy * 112 + ix] : 0.f;
      }
    }
    float hv[8];
#pragma unroll
    for (int c = 0; c < 8; ++c) {
      f32x2 sA = {0.f, 0.f};  // (s00, s01)
      f32x2 sB = {0.f, 0.f};  // (s10, s11)
#pragma unroll
      for (int ty = 0; ty < 3; ++ty)
#pragma unroll
        for (int tx = 0; tx < 3; ++tx) {
          float wk = w1[c * 9 + ty * 3 + tx];
          f32x2 wkk = {wk, wk};
          f32x2 xa = {win[ty][tx], win[ty][tx + 1]};
          f32x2 xb2 = {win[ty + 1][tx], win[ty + 1][tx + 1]};
          sA = __builtin_elementwise_fma(xa, wkk, sA);
          sB = __builtin_elementwise_fma(xb2, wkk, sB);
        }
      f32x2 sm = __builtin_elementwise_max(sA, sB);
      float m = fmaxf(sm.x, sm.y);
      hv[c] = fmaxf(m + b1[c], 0.f);
    }
#pragma unroll
    for (int cp = 0; cp < 4; ++cp)
      hsu[(cp * NROWS + r) * HSTR + 1 + hc] = pack_f16(hv[2 * cp], hv[2 * cp + 1]);
  }
  __syncthreads();

  // ---- P2: conv2+pool+relu via MFMA; fv -> fsu; chunked patch reduce ----
  {
    int offs[12];
#pragma unroll
    for (int kk = 0; kk < 3; ++kk)
#pragma unroll
      for (int i = 0; i < 4; ++i) {
        int k32 = kk * 16 + q * 4 + i;
        int icp = k32 / 9, tap = k32 - icp * 9;
        int ty = tap / 3, tx = tap - ty * 3;
        offs[kk * 4 + i] = (icp * NROWS + ty) * HSTR + tx;  // junk if k32>=36
      }
    const int yoff = 2 * ((l >> 3) & 1) + ((l >> 1) & 1);  // 2a+dy
    const int xoff = 2 * ((l >> 2) & 1) + (l & 1);         // 2b+dx
    const float b2v = b2[l & 15];
    _Float16* fsh = (_Float16*)fsu;

#pragma unroll 1
    for (int c = 0; c < 2; ++c) {  // chunk: patches c*49 .. c*49+48
#pragma unroll 2
      for (int p_l = wv; p_l < 49; p_l += 4) {
        int p = c * 49 + p_l;
        int py = p / 14, px = p - py * 14;
        int base = (4 * py + yoff) * HSTR + 4 * px + xoff;
        uint4 a0u, a1u, a2u = make_uint4(0u, 0u, 0u, 0u);
        a0u.x = hsu[base + offs[0]];
        a0u.y = hsu[base + offs[1]];
        a0u.z = hsu[base + offs[2]];
        a0u.w = hsu[base + offs[3]];
        a1u.x = hsu[base + offs[4]];
        a1u.y = hsu[base + offs[5]];
        a1u.z = hsu[base + offs[6]];
        a1u.w = hsu[base + offs[7]];
        if (q == 0) {  // only k32 32..35 real in K-step 2
          a2u.x = hsu[base + offs[8]];
          a2u.y = hsu[base + offs[9]];
          a2u.z = hsu[base + offs[10]];
          a2u.w = hsu[base + offs[11]];
        }
        f32x4 acc = {0.f, 0.f, 0.f, 0.f};
        acc = __builtin_amdgcn_mfma_f32_16x16x32_f16(as_f16x8(a0u), as_f16x8(bu[0]), acc, 0, 0, 0);
        acc = __builtin_amdgcn_mfma_f32_16x16x32_f16(as_f16x8(a1u), as_f16x8(bu[1]), acc, 0, 0, 0);
        acc = __builtin_amdgcn_mfma_f32_16x16x32_f16(as_f16x8(a2u), as_f16x8(bu[2]), acc, 0, 0, 0);
        float mx = fmaxf(fmaxf(acc[0], acc[1]), fmaxf(acc[2], acc[3]));
        float fv = fmaxf(mx + b2v, 0.f);  // f[oc=l&15][f-pixel fmem=q of patch p]
        fsh[p_l * (2 * FSTR) + l] = (_Float16)fv;
      }
      __syncthreads();
      // chunk reduce: thread t<196 -> (row=p_l, ot); 32 fdot2 over 64 lanes
      if (tid < 196) {
        int row = tid >> 2, ot = tid & 3;
        int p = c * 49 + row;
        const unsigned* fr = fsu + row * FSTR;
        float acc = 0.f;
#pragma unroll
        for (int i = 0; i < 32; ++i) acc = fdot2_(as_h2(fr[i]), as_h2(wpk[i]), acc);
        pfl[p * 4 + ot] = acc + bpv;
      }
      __syncthreads();
    }
  }

  // ---- P3: fc1 partial over this tile's pf slice [392s, 392s+392) ----
  {
    int j = tid >> 2, q4 = tid & 3;
    const float2* wrow = (const float2*)(w_fc1 + j * 784 + 392 * s + q4 * 98);
    const float2* pv = (const float2*)(pfl + q4 * 98);
    float acc = 0.f;
#pragma unroll 7
    for (int m = 0; m < 49; ++m) {
      float2 wv2 = wrow[m], fv2 = pv[m];
      acc += wv2.x * fv2.x + wv2.y * fv2.y;
    }
    acc += __shfl_down(acc, 2, 4);
    acc += __shfl_down(acc, 1, 4);
    if (q4 == 0) h1p[((long)b * 2 + s) * 64 + j] = acc;
  }
}

// ---------------- k_tail: combine partials + fc2 + log_softmax --------------
__global__ __launch_bounds__(64) void k_tail(const float* __restrict__ h1p,
                                             const float* __restrict__ b_fc1,
                                             const float* __restrict__ w_fc2,
                                             const float* __restrict__ b_fc2,
                                             float* __restrict__ out) {
  __shared__ float h1s[64];
  __shared__ float red[11];
  int b = blockIdx.x, j = threadIdx.x;
  float v = b_fc1[j] + h1p[(long)b * 128 + j] + h1p[(long)b * 128 + 64 + j];
  h1s[j] = fmaxf(v, 0.f);
  __syncthreads();
  if (j < 10) {
    float acc = b_fc2[j];
    const float* wo = w_fc2 + j * 64;
#pragma unroll
    for (int k = 0; k < 64; ++k) acc += h1s[k] * wo[k];
    red[j] = acc;
  }
  __syncthreads();
  if (j == 0) {
    float mx = red[0];
    for (int o = 1; o < 10; ++o) mx = fmaxf(mx, red[o]);
    float se = 0.f;
    for (int o = 0; o < 10; ++o) se += expf(red[o] - mx);
    red[10] = mx + logf(se);
  }
  __syncthreads();
  if (j < 10) out[b * 10 + j] = red[j] - red[10];
}

extern "C" void kernel_launch(void* const* d_in, const int* in_sizes, int n_in,
                              void* d_out, int out_size, void* d_ws, size_t ws_size,
                              hipStream_t stream) {
  const float* x = (const float*)d_in[0];
  const float* w1 = (const float*)d_in[1];
  const float* b1 = (const float*)d_in[2];
  const float* w2 = (const float*)d_in[3];
  const float* b2 = (const float*)d_in[4];
  const float* wp = (const float*)d_in[5];
  const float* bp = (const float*)d_in[6];
  const float* wf1 = (const float*)d_in[7];
  const float* bf1 = (const float*)d_in[8];
  const float* wf2 = (const float*)d_in[9];
  const float* bf2 = (const float*)d_in[10];

  float* h1p = (float*)d_ws;  // [512][2][64] = 65536 floats (256 KB)

  k_fused<<<dim3(1024), 256, 0, stream>>>(x, w1, b1, w2, b2, wp, bp, wf1, h1p);
  k_tail<<<dim3(512), 64, 0, stream>>>(h1p, bf1, wf2, bf2, (float*)d_out);
}

// Round 16
// 127.591 us; speedup vs baseline: 1.6590x; 1.0520x over previous
//
#include <hip/hip_runtime.h>

// R13 configuration (best measured: 126.3 us total, k_fused 48 us, no spill).
//   k_prew: repack w2 -> bw u32[16 oc][48] f16 ic-pairs (k-order icp*9+tap, 36..47=0)
//   k_fused (grid 1024 = b*2+s, 256 thr, 4 blocks/CU):
//     P1 conv1+relu+pool via packed-f32 -> LDS f16 h-tile hsu[4][30][58]
//     P2 conv2+pool+relu via mfma_f32_16x16x32_f16 (strip = one 2x2 patch,
//        A gathered from hsu via 12 ds_read_b32; B-frags = 3x uint4 global loads);
//        fv -> fsu rows; chunk-reduce via fdot2 -> pfl[392]
//     P3 fc1 partial -> h1p[b][s][64]
//   k_tail: h1 = relu(sum_s h1p + b_fc1); fc2; log_softmax -> out[512,10]
// Lessons pinned: (R14) no device-scope fence/atomic cross-block sync (XCD L2
// writeback storm); (R15) no in-kernel B-pack / unroll-2 (VGPR 56 -> 64 = spill,
// 7.4 MB scratch traffic). Launch count is ~free (fixed ~70 us harness floor).

#define HSTR 58   // 56 cols + 2 halo cols (u32 units)
#define NROWS 30  // 28 tile h-rows + 2 halo
#define FSTR 33   // fsu row stride in u32 (66 f16) -> conflict-free reduce

typedef _Float16 half2_t __attribute__((ext_vector_type(2)));
typedef _Float16 f16x8 __attribute__((ext_vector_type(8)));
typedef float f32x4 __attribute__((ext_vector_type(4)));
typedef float f32x2 __attribute__((ext_vector_type(2)));

__device__ __forceinline__ unsigned pack_f16(float a, float b) {
  union { half2_t h; unsigned u; } z;
  z.h[0] = (_Float16)a;
  z.h[1] = (_Float16)b;
  return z.u;
}

__device__ __forceinline__ half2_t as_h2(unsigned u) {
  union { unsigned u; half2_t h; } z;
  z.u = u;
  return z.h;
}

__device__ __forceinline__ f16x8 as_f16x8(uint4 u) {
  union { uint4 u; f16x8 f; } z;
  z.u = u;
  return z.f;
}

__device__ __forceinline__ float fdot2_(half2_t a, half2_t b, float c) {
#if __has_builtin(__builtin_amdgcn_fdot2)
  return __builtin_amdgcn_fdot2(a, b, c, false);
#else
  return c + (float)a[0] * (float)b[0] + (float)a[1] * (float)b[1];
#endif
}

// ---------------- k_prew: repack conv2 weights for MFMA B-operand ----------
__global__ __launch_bounds__(256) void k_prew(const float* __restrict__ w2,
                                              unsigned* __restrict__ bw) {
  int t = blockIdx.x * 256 + threadIdx.x;
  if (t < 768) {
    int oc = t / 48, k32 = t % 48;
    unsigned v = 0u;
    if (k32 < 36) {
      int icp = k32 / 9, tap = k32 - icp * 9;
      v = pack_f16(w2[(oc * 8 + 2 * icp) * 9 + tap],
                   w2[(oc * 8 + 2 * icp + 1) * 9 + tap]);
    }
    bw[t] = v;
  }
}

__global__ __launch_bounds__(256, 4) void k_fused(
    const float* __restrict__ x, const float* __restrict__ w1,
    const float* __restrict__ b1, const unsigned* __restrict__ bw,
    const float* __restrict__ b2, const float* __restrict__ wp,
    const float* __restrict__ bp, const float* __restrict__ w_fc1,
    float* __restrict__ h1p) {
  __shared__ __align__(16) unsigned hsu[4 * NROWS * HSTR];  // 27.2 KB
  __shared__ __align__(16) unsigned fsu[49 * FSTR];         // 6.3 KB (f16 rows)
  __shared__ __align__(16) float pfl[392];                  // 1.6 KB
  const int tid = threadIdx.x;
  const int b = blockIdx.x >> 1;
  const int s = blockIdx.x & 1;
  const int l = tid & 63;
  const int wv = __builtin_amdgcn_readfirstlane(tid >> 6);  // wave id 0..3
  const float* xb = x + (long)b * 12544;

  // Per-thread packed wp pairs for the chunk-reduce: this thread's ot = tid&3.
  // pair i covers lanes (2i, 2i+1); lane l -> wp[ot*64 + (l&15)*4 + (l>>4)].
  unsigned wpk[32];
  {
    int ot0 = tid & 3;
#pragma unroll
    for (int i = 0; i < 32; ++i) {
      int l0 = 2 * i, l1 = 2 * i + 1;
      wpk[i] = pack_f16(wp[ot0 * 64 + (l0 & 15) * 4 + (l0 >> 4)],
                        wp[ot0 * 64 + (l1 & 15) * 4 + (l1 >> 4)]);
    }
  }
  const float bpv = bp[tid & 3];

  for (int i = tid; i < 4 * NROWS * HSTR; i += 256) hsu[i] = 0u;
  __syncthreads();

  // ---- P1: conv1(1->8)+bias+relu+maxpool2 (packed f32) -> f16 LDS tile ----
  for (int task = tid; task < 1680; task += 256) {
    int r = task / 56, hc = task % 56;
    int gr = 28 * s - 1 + r;
    if ((unsigned)gr >= 56u) continue;
    float win[4][4];
    int iy0 = 2 * gr - 1, ix0 = 2 * hc - 1;
#pragma unroll
    for (int rr = 0; rr < 4; ++rr) {
      int iy = iy0 + rr;
      bool yok = (unsigned)iy < 112u;
#pragma unroll
      for (int qq = 0; qq < 4; ++qq) {
        int ix = ix0 + qq;
        win[rr][qq] = (yok && (unsigned)ix < 112u) ? xb[iy * 112 + ix] : 0.f;
      }
    }
    float hv[8];
#pragma unroll
    for (int c = 0; c < 8; ++c) {
      f32x2 sA = {0.f, 0.f};  // (s00, s01)
      f32x2 sB = {0.f, 0.f};  // (s10, s11)
#pragma unroll
      for (int ty = 0; ty < 3; ++ty)
#pragma unroll
        for (int tx = 0; tx < 3; ++tx) {
          float wk = w1[c * 9 + ty * 3 + tx];
          f32x2 wkk = {wk, wk};
          f32x2 xa = {win[ty][tx], win[ty][tx + 1]};
          f32x2 xb2 = {win[ty + 1][tx], win[ty + 1][tx + 1]};
          sA = __builtin_elementwise_fma(xa, wkk, sA);
          sB = __builtin_elementwise_fma(xb2, wkk, sB);
        }
      f32x2 sm = __builtin_elementwise_max(sA, sB);
      float m = fmaxf(sm.x, sm.y);
      hv[c] = fmaxf(m + b1[c], 0.f);
    }
#pragma unroll
    for (int cp = 0; cp < 4; ++cp)
      hsu[(cp * NROWS + r) * HSTR + 1 + hc] = pack_f16(hv[2 * cp], hv[2 * cp + 1]);
  }
  __syncthreads();

  // ---- P2: conv2+pool+relu via MFMA; fv -> fsu; chunked patch reduce ----
  {
    const int q = l >> 4;  // k-octet / fmem role
    int offs[12];
#pragma unroll
    for (int kk = 0; kk < 3; ++kk)
#pragma unroll
      for (int i = 0; i < 4; ++i) {
        int k32 = kk * 16 + q * 4 + i;
        int icp = k32 / 9, tap = k32 - icp * 9;
        int ty = tap / 3, tx = tap - ty * 3;
        offs[kk * 4 + i] = (icp * NROWS + ty) * HSTR + tx;  // junk if k32>=36
      }
    const int yoff = 2 * ((l >> 3) & 1) + ((l >> 1) & 1);  // 2a+dy
    const int xoff = 2 * ((l >> 2) & 1) + (l & 1);         // 2b+dx
    uint4 bu0 = *(const uint4*)(bw + (l & 15) * 48 + 0 * 16 + q * 4);
    uint4 bu1 = *(const uint4*)(bw + (l & 15) * 48 + 1 * 16 + q * 4);
    uint4 bu2 = *(const uint4*)(bw + (l & 15) * 48 + 2 * 16 + q * 4);
    const float b2v = b2[l & 15];
    _Float16* fsh = (_Float16*)fsu;

#pragma unroll 1
    for (int c = 0; c < 2; ++c) {  // chunk: patches c*49 .. c*49+48
#pragma unroll 1
      for (int p_l = wv; p_l < 49; p_l += 4) {
        int p = c * 49 + p_l;
        int py = p / 14, px = p - py * 14;
        int base = (4 * py + yoff) * HSTR + 4 * px + xoff;
        uint4 a0u, a1u, a2u = make_uint4(0u, 0u, 0u, 0u);
        a0u.x = hsu[base + offs[0]];
        a0u.y = hsu[base + offs[1]];
        a0u.z = hsu[base + offs[2]];
        a0u.w = hsu[base + offs[3]];
        a1u.x = hsu[base + offs[4]];
        a1u.y = hsu[base + offs[5]];
        a1u.z = hsu[base + offs[6]];
        a1u.w = hsu[base + offs[7]];
        if (q == 0) {  // only k32 32..35 real in K-step 2
          a2u.x = hsu[base + offs[8]];
          a2u.y = hsu[base + offs[9]];
          a2u.z = hsu[base + offs[10]];
          a2u.w = hsu[base + offs[11]];
        }
        f32x4 acc = {0.f, 0.f, 0.f, 0.f};
        acc = __builtin_amdgcn_mfma_f32_16x16x32_f16(as_f16x8(a0u), as_f16x8(bu0), acc, 0, 0, 0);
        acc = __builtin_amdgcn_mfma_f32_16x16x32_f16(as_f16x8(a1u), as_f16x8(bu1), acc, 0, 0, 0);
        acc = __builtin_amdgcn_mfma_f32_16x16x32_f16(as_f16x8(a2u), as_f16x8(bu2), acc, 0, 0, 0);
        float mx = fmaxf(fmaxf(acc[0], acc[1]), fmaxf(acc[2], acc[3]));
        float fv = fmaxf(mx + b2v, 0.f);  // f[oc=l&15][f-pixel fmem=q of patch p]
        fsh[p_l * (2 * FSTR) + l] = (_Float16)fv;
      }
      __syncthreads();
      // chunk reduce: thread t<196 -> (row=p_l, ot); 32 fdot2 over 64 lanes
      if (tid < 196) {
        int row = tid >> 2, ot = tid & 3;
        int p = c * 49 + row;
        const unsigned* fr = fsu + row * FSTR;
        float acc = 0.f;
#pragma unroll
        for (int i = 0; i < 32; ++i) acc = fdot2_(as_h2(fr[i]), as_h2(wpk[i]), acc);
        pfl[p * 4 + ot] = acc + bpv;
      }
      __syncthreads();
    }
  }

  // ---- P3: fc1 partial over this tile's pf slice [392s, 392s+392) ----
  {
    int j = tid >> 2, q4 = tid & 3;
    const float2* wrow = (const float2*)(w_fc1 + j * 784 + 392 * s + q4 * 98);
    const float2* pv = (const float2*)(pfl + q4 * 98);
    float acc = 0.f;
#pragma unroll 7
    for (int m = 0; m < 49; ++m) {
      float2 wv2 = wrow[m], fv2 = pv[m];
      acc += wv2.x * fv2.x + wv2.y * fv2.y;
    }
    acc += __shfl_down(acc, 2, 4);
    acc += __shfl_down(acc, 1, 4);
    if (q4 == 0) h1p[((long)b * 2 + s) * 64 + j] = acc;
  }
}

// ---------------- k_tail: combine partials + fc2 + log_softmax --------------
__global__ __launch_bounds__(64) void k_tail(const float* __restrict__ h1p,
                                             const float* __restrict__ b_fc1,
                                             const float* __restrict__ w_fc2,
                                             const float* __restrict__ b_fc2,
                                             float* __restrict__ out) {
  __shared__ float h1s[64];
  __shared__ float red[11];
  int b = blockIdx.x, j = threadIdx.x;
  float v = b_fc1[j] + h1p[(long)b * 128 + j] + h1p[(long)b * 128 + 64 + j];
  h1s[j] = fmaxf(v, 0.f);
  __syncthreads();
  if (j < 10) {
    float acc = b_fc2[j];
    const float* wo = w_fc2 + j * 64;
#pragma unroll
    for (int k = 0; k < 64; ++k) acc += h1s[k] * wo[k];
    red[j] = acc;
  }
  __syncthreads();
  if (j == 0) {
    float mx = red[0];
    for (int o = 1; o < 10; ++o) mx = fmaxf(mx, red[o]);
    float se = 0.f;
    for (int o = 0; o < 10; ++o) se += expf(red[o] - mx);
    red[10] = mx + logf(se);
  }
  __syncthreads();
  if (j < 10) out[b * 10 + j] = red[j] - red[10];
}

extern "C" void kernel_launch(void* const* d_in, const int* in_sizes, int n_in,
                              void* d_out, int out_size, void* d_ws, size_t ws_size,
                              hipStream_t stream) {
  const float* x = (const float*)d_in[0];
  const float* w1 = (const float*)d_in[1];
  const float* b1 = (const float*)d_in[2];
  const float* w2 = (const float*)d_in[3];
  const float* b2 = (const float*)d_in[4];
  const float* wp = (const float*)d_in[5];
  const float* bp = (const float*)d_in[6];
  const float* wf1 = (const float*)d_in[7];
  const float* bf1 = (const float*)d_in[8];
  const float* wf2 = (const float*)d_in[9];
  const float* bf2 = (const float*)d_in[10];

  float* h1p = (float*)d_ws;                // [512][2][64] = 65536 floats
  unsigned* bw = (unsigned*)(h1p + 65536);  // [768] packed MFMA B weights

  k_prew<<<dim3(3), 256, 0, stream>>>(w2, bw);
  k_fused<<<dim3(1024), 256, 0, stream>>>(x, w1, b1, bw, b2, wp, bp, wf1, h1p);
  k_tail<<<dim3(512), 64, 0, stream>>>(h1p, bf1, wf2, bf2, (float*)d_out);
}

// Round 17
// 125.086 us; speedup vs baseline: 1.6923x; 1.0200x over previous
//
#include <hip/hip_runtime.h>

// R13/R16 structure with k_prew folded in via LDS (no VGPR liveness cost):
//   k_fused (grid 1024 = b*2+s, 256 thr, 4 blocks/CU):
//     init: zero hsu; pack w2 -> bwl[768] LDS (f16 ic-pairs, k-order icp*9+tap)
//     P1 conv1+relu+pool via packed-f32 -> LDS f16 h-tile hsu[4][30][58]
//     P2 conv2+pool+relu via mfma_f32_16x16x32_f16 (strip = one 2x2 patch,
//        A gathered from hsu via 12 ds_read_b32; B-frags = 3x ds_read_b128 from bwl);
//        fv -> fsu rows; chunk-reduce via fdot2 -> pfl[392]
//     P3 fc1 partial -> h1p[b][s][64]
//   k_tail: h1 = relu(sum_s h1p + b_fc1); fc2; log_softmax -> out[512,10]
// Pinned lessons: (R14) no device-scope fence/atomic cross-block sync;
// (R15) no extra long-lived VGPR state at (256,4) — VGPR 56 is saturated.

#define HSTR 58   // 56 cols + 2 halo cols (u32 units)
#define NROWS 30  // 28 tile h-rows + 2 halo
#define FSTR 33   // fsu row stride in u32 (66 f16) -> conflict-free reduce

typedef _Float16 half2_t __attribute__((ext_vector_type(2)));
typedef _Float16 f16x8 __attribute__((ext_vector_type(8)));
typedef float f32x4 __attribute__((ext_vector_type(4)));
typedef float f32x2 __attribute__((ext_vector_type(2)));

__device__ __forceinline__ unsigned pack_f16(float a, float b) {
  union { half2_t h; unsigned u; } z;
  z.h[0] = (_Float16)a;
  z.h[1] = (_Float16)b;
  return z.u;
}

__device__ __forceinline__ half2_t as_h2(unsigned u) {
  union { unsigned u; half2_t h; } z;
  z.u = u;
  return z.h;
}

__device__ __forceinline__ f16x8 as_f16x8(uint4 u) {
  union { uint4 u; f16x8 f; } z;
  z.u = u;
  return z.f;
}

__device__ __forceinline__ float fdot2_(half2_t a, half2_t b, float c) {
#if __has_builtin(__builtin_amdgcn_fdot2)
  return __builtin_amdgcn_fdot2(a, b, c, false);
#else
  return c + (float)a[0] * (float)b[0] + (float)a[1] * (float)b[1];
#endif
}

__global__ __launch_bounds__(256, 4) void k_fused(
    const float* __restrict__ x, const float* __restrict__ w1,
    const float* __restrict__ b1, const float* __restrict__ w2,
    const float* __restrict__ b2, const float* __restrict__ wp,
    const float* __restrict__ bp, const float* __restrict__ w_fc1,
    float* __restrict__ h1p) {
  __shared__ __align__(16) unsigned hsu[4 * NROWS * HSTR];  // 27.2 KB
  __shared__ __align__(16) unsigned bwl[768];               // 3.0 KB B-frags
  __shared__ __align__(16) unsigned fsu[49 * FSTR];         // 6.3 KB (f16 rows)
  __shared__ __align__(16) float pfl[392];                  // 1.6 KB
  const int tid = threadIdx.x;
  const int b = blockIdx.x >> 1;
  const int s = blockIdx.x & 1;
  const int l = tid & 63;
  const int wv = __builtin_amdgcn_readfirstlane(tid >> 6);  // wave id 0..3
  const float* xb = x + (long)b * 12544;

  // Per-thread packed wp pairs for the chunk-reduce: this thread's ot = tid&3.
  // pair i covers lanes (2i, 2i+1); lane l -> wp[ot*64 + (l&15)*4 + (l>>4)].
  unsigned wpk[32];
  {
    int ot0 = tid & 3;
#pragma unroll
    for (int i = 0; i < 32; ++i) {
      int l0 = 2 * i, l1 = 2 * i + 1;
      wpk[i] = pack_f16(wp[ot0 * 64 + (l0 & 15) * 4 + (l0 >> 4)],
                        wp[ot0 * 64 + (l1 & 15) * 4 + (l1 >> 4)]);
    }
  }
  const float bpv = bp[tid & 3];

  for (int i = tid; i < 4 * NROWS * HSTR; i += 256) hsu[i] = 0u;
  // Pack conv2 weights into LDS (was k_prew): 3 entries per thread.
  for (int t = tid; t < 768; t += 256) {
    int oc = t / 48, k32 = t % 48;
    unsigned v = 0u;
    if (k32 < 36) {
      int icp = k32 / 9, tap = k32 - icp * 9;
      v = pack_f16(w2[(oc * 8 + 2 * icp) * 9 + tap],
                   w2[(oc * 8 + 2 * icp + 1) * 9 + tap]);
    }
    bwl[t] = v;
  }
  __syncthreads();

  // ---- P1: conv1(1->8)+bias+relu+maxpool2 (packed f32) -> f16 LDS tile ----
  for (int task = tid; task < 1680; task += 256) {
    int r = task / 56, hc = task % 56;
    int gr = 28 * s - 1 + r;
    if ((unsigned)gr >= 56u) continue;
    float win[4][4];
    int iy0 = 2 * gr - 1, ix0 = 2 * hc - 1;
#pragma unroll
    for (int rr = 0; rr < 4; ++rr) {
      int iy = iy0 + rr;
      bool yok = (unsigned)iy < 112u;
#pragma unroll
      for (int qq = 0; qq < 4; ++qq) {
        int ix = ix0 + qq;
        win[rr][qq] = (yok && (unsigned)ix < 112u) ? xb[iy * 112 + ix] : 0.f;
      }
    }
    float hv[8];
#pragma unroll
    for (int c = 0; c < 8; ++c) {
      f32x2 sA = {0.f, 0.f};  // (s00, s01)
      f32x2 sB = {0.f, 0.f};  // (s10, s11)
#pragma unroll
      for (int ty = 0; ty < 3; ++ty)
#pragma unroll
        for (int tx = 0; tx < 3; ++tx) {
          float wk = w1[c * 9 + ty * 3 + tx];
          f32x2 wkk = {wk, wk};
          f32x2 xa = {win[ty][tx], win[ty][tx + 1]};
          f32x2 xb2 = {win[ty + 1][tx], win[ty + 1][tx + 1]};
          sA = __builtin_elementwise_fma(xa, wkk, sA);
          sB = __builtin_elementwise_fma(xb2, wkk, sB);
        }
      f32x2 sm = __builtin_elementwise_max(sA, sB);
      float m = fmaxf(sm.x, sm.y);
      hv[c] = fmaxf(m + b1[c], 0.f);
    }
#pragma unroll
    for (int cp = 0; cp < 4; ++cp)
      hsu[(cp * NROWS + r) * HSTR + 1 + hc] = pack_f16(hv[2 * cp], hv[2 * cp + 1]);
  }
  __syncthreads();

  // ---- P2: conv2+pool+relu via MFMA; fv -> fsu; chunked patch reduce ----
  {
    const int q = l >> 4;  // k-octet / fmem role
    int offs[12];
#pragma unroll
    for (int kk = 0; kk < 3; ++kk)
#pragma unroll
      for (int i = 0; i < 4; ++i) {
        int k32 = kk * 16 + q * 4 + i;
        int icp = k32 / 9, tap = k32 - icp * 9;
        int ty = tap / 3, tx = tap - ty * 3;
        offs[kk * 4 + i] = (icp * NROWS + ty) * HSTR + tx;  // junk if k32>=36
      }
    const int yoff = 2 * ((l >> 3) & 1) + ((l >> 1) & 1);  // 2a+dy
    const int xoff = 2 * ((l >> 2) & 1) + (l & 1);         // 2b+dx
    uint4 bu0 = *(const uint4*)(bwl + (l & 15) * 48 + 0 * 16 + q * 4);
    uint4 bu1 = *(const uint4*)(bwl + (l & 15) * 48 + 1 * 16 + q * 4);
    uint4 bu2 = *(const uint4*)(bwl + (l & 15) * 48 + 2 * 16 + q * 4);
    const float b2v = b2[l & 15];
    _Float16* fsh = (_Float16*)fsu;

#pragma unroll 1
    for (int c = 0; c < 2; ++c) {  // chunk: patches c*49 .. c*49+48
#pragma unroll 1
      for (int p_l = wv; p_l < 49; p_l += 4) {
        int p = c * 49 + p_l;
        int py = p / 14, px = p - py * 14;
        int base = (4 * py + yoff) * HSTR + 4 * px + xoff;
        uint4 a0u, a1u, a2u = make_uint4(0u, 0u, 0u, 0u);
        a0u.x = hsu[base + offs[0]];
        a0u.y = hsu[base + offs[1]];
        a0u.z = hsu[base + offs[2]];
        a0u.w = hsu[base + offs[3]];
        a1u.x = hsu[base + offs[4]];
        a1u.y = hsu[base + offs[5]];
        a1u.z = hsu[base + offs[6]];
        a1u.w = hsu[base + offs[7]];
        if (q == 0) {  // only k32 32..35 real in K-step 2
          a2u.x = hsu[base + offs[8]];
          a2u.y = hsu[base + offs[9]];
          a2u.z = hsu[base + offs[10]];
          a2u.w = hsu[base + offs[11]];
        }
        f32x4 acc = {0.f, 0.f, 0.f, 0.f};
        acc = __builtin_amdgcn_mfma_f32_16x16x32_f16(as_f16x8(a0u), as_f16x8(bu0), acc, 0, 0, 0);
        acc = __builtin_amdgcn_mfma_f32_16x16x32_f16(as_f16x8(a1u), as_f16x8(bu1), acc, 0, 0, 0);
        acc = __builtin_amdgcn_mfma_f32_16x16x32_f16(as_f16x8(a2u), as_f16x8(bu2), acc, 0, 0, 0);
        float mx = fmaxf(fmaxf(acc[0], acc[1]), fmaxf(acc[2], acc[3]));
        float fv = fmaxf(mx + b2v, 0.f);  // f[oc=l&15][f-pixel fmem=q of patch p]
        fsh[p_l * (2 * FSTR) + l] = (_Float16)fv;
      }
      __syncthreads();
      // chunk reduce: thread t<196 -> (row=p_l, ot); 32 fdot2 over 64 lanes
      if (tid < 196) {
        int row = tid >> 2, ot = tid & 3;
        int p = c * 49 + row;
        const unsigned* fr = fsu + row * FSTR;
        float acc = 0.f;
#pragma unroll
        for (int i = 0; i < 32; ++i) acc = fdot2_(as_h2(fr[i]), as_h2(wpk[i]), acc);
        pfl[p * 4 + ot] = acc + bpv;
      }
      __syncthreads();
    }
  }

  // ---- P3: fc1 partial over this tile's pf slice [392s, 392s+392) ----
  {
    int j = tid >> 2, q4 = tid & 3;
    const float2* wrow = (const float2*)(w_fc1 + j * 784 + 392 * s + q4 * 98);
    const float2* pv = (const float2*)(pfl + q4 * 98);
    float acc = 0.f;
#pragma unroll 7
    for (int m = 0; m < 49; ++m) {
      float2 wv2 = wrow[m], fv2 = pv[m];
      acc += wv2.x * fv2.x + wv2.y * fv2.y;
    }
    acc += __shfl_down(acc, 2, 4);
    acc += __shfl_down(acc, 1, 4);
    if (q4 == 0) h1p[((long)b * 2 + s) * 64 + j] = acc;
  }
}

// ---------------- k_tail: combine partials + fc2 + log_softmax --------------
__global__ __launch_bounds__(64) void k_tail(const float* __restrict__ h1p,
                                             const float* __restrict__ b_fc1,
                                             const float* __restrict__ w_fc2,
                                             const float* __restrict__ b_fc2,
                                             float* __restrict__ out) {
  __shared__ float h1s[64];
  __shared__ float red[11];
  int b = blockIdx.x, j = threadIdx.x;
  float v = b_fc1[j] + h1p[(long)b * 128 + j] + h1p[(long)b * 128 + 64 + j];
  h1s[j] = fmaxf(v, 0.f);
  __syncthreads();
  if (j < 10) {
    float acc = b_fc2[j];
    const float* wo = w_fc2 + j * 64;
#pragma unroll
    for (int k = 0; k < 64; ++k) acc += h1s[k] * wo[k];
    red[j] = acc;
  }
  __syncthreads();
  if (j == 0) {
    float mx = red[0];
    for (int o = 1; o < 10; ++o) mx = fmaxf(mx, red[o]);
    float se = 0.f;
    for (int o = 0; o < 10; ++o) se += expf(red[o] - mx);
    red[10] = mx + logf(se);
  }
  __syncthreads();
  if (j < 10) out[b * 10 + j] = red[j] - red[10];
}

extern "C" void kernel_launch(void* const* d_in, const int* in_sizes, int n_in,
                              void* d_out, int out_size, void* d_ws, size_t ws_size,
                              hipStream_t stream) {
  const float* x = (const float*)d_in[0];
  const float* w1 = (const float*)d_in[1];
  const float* b1 = (const float*)d_in[2];
  const float* w2 = (const float*)d_in[3];
  const float* b2 = (const float*)d_in[4];
  const float* wp = (const float*)d_in[5];
  const float* bp = (const float*)d_in[6];
  const float* wf1 = (const float*)d_in[7];
  const float* bf1 = (const float*)d_in[8];
  const float* wf2 = (const float*)d_in[9];
  const float* bf2 = (const float*)d_in[10];

  float* h1p = (float*)d_ws;  // [512][2][64] = 65536 floats (256 KB)

  k_fused<<<dim3(1024), 256, 0, stream>>>(x, w1, b1, w2, b2, wp, bp, wf1, h1p);
  k_tail<<<dim3(512), 64, 0, stream>>>(h1p, bf1, wf2, bf2, (float*)d_out);
}

// Round 18
// 119.998 us; speedup vs baseline: 1.7640x; 1.0424x over previous
//
#include <hip/hip_runtime.h>

// R17 structure + wpk moved to LDS (frees ~32 live VGPRs) + strip-loop unroll x2:
//   k_fused (grid 1024 = b*2+s, 256 thr, 4 blocks/CU):
//     init: zero hsu; pack w2 -> bwl[768] LDS; pack wp -> wps[128] LDS (4 ot-rows)
//     P1 conv1+relu+pool via packed-f32 -> LDS f16 h-tile hsu[4][30][58]
//     P2 conv2+pool+relu via mfma_f32_16x16x32_f16 (strip = one 2x2 patch,
//        A via 12 ds_read_b32, B via 3x ds_read_b128 from bwl; unroll x2 for ILP);
//        fv -> fsu rows; chunk-reduce via fdot2 (weights from wps) -> pfl[392]
//     P3 fc1 partial -> h1p[b][s][64]
//   k_tail: h1 = relu(sum_s h1p + b_fc1); fc2; log_softmax -> out[512,10]
// Pinned lessons: (R14) no device-scope fence/atomic cross-block sync;
// (R15) long-lived VGPR state at this config spills -> scratch traffic; watch
// WRITE_SIZE (must stay ~256 B).

#define HSTR 58   // 56 cols + 2 halo cols (u32 units)
#define NROWS 30  // 28 tile h-rows + 2 halo
#define FSTR 33   // fsu row stride in u32 (66 f16) -> conflict-free reduce

typedef _Float16 half2_t __attribute__((ext_vector_type(2)));
typedef _Float16 f16x8 __attribute__((ext_vector_type(8)));
typedef float f32x4 __attribute__((ext_vector_type(4)));
typedef float f32x2 __attribute__((ext_vector_type(2)));

__device__ __forceinline__ unsigned pack_f16(float a, float b) {
  union { half2_t h; unsigned u; } z;
  z.h[0] = (_Float16)a;
  z.h[1] = (_Float16)b;
  return z.u;
}

__device__ __forceinline__ half2_t as_h2(unsigned u) {
  union { unsigned u; half2_t h; } z;
  z.u = u;
  return z.h;
}

__device__ __forceinline__ f16x8 as_f16x8(uint4 u) {
  union { uint4 u; f16x8 f; } z;
  z.u = u;
  return z.f;
}

__device__ __forceinline__ float fdot2_(half2_t a, half2_t b, float c) {
#if __has_builtin(__builtin_amdgcn_fdot2)
  return __builtin_amdgcn_fdot2(a, b, c, false);
#else
  return c + (float)a[0] * (float)b[0] + (float)a[1] * (float)b[1];
#endif
}

__global__ __launch_bounds__(256, 4) void k_fused(
    const float* __restrict__ x, const float* __restrict__ w1,
    const float* __restrict__ b1, const float* __restrict__ w2,
    const float* __restrict__ b2, const float* __restrict__ wp,
    const float* __restrict__ bp, const float* __restrict__ w_fc1,
    float* __restrict__ h1p) {
  __shared__ __align__(16) unsigned hsu[4 * NROWS * HSTR];  // 27.2 KB
  __shared__ __align__(16) unsigned bwl[768];               // 3.0 KB B-frags
  __shared__ __align__(16) unsigned wps[128];               // 0.5 KB wp pairs [i][ot]
  __shared__ __align__(16) unsigned fsu[49 * FSTR];         // 6.3 KB (f16 rows)
  __shared__ __align__(16) float pfl[392];                  // 1.6 KB
  const int tid = threadIdx.x;
  const int b = blockIdx.x >> 1;
  const int s = blockIdx.x & 1;
  const int l = tid & 63;
  const int wv = __builtin_amdgcn_readfirstlane(tid >> 6);  // wave id 0..3
  const float* xb = x + (long)b * 12544;
  const float bpv = bp[tid & 3];

  for (int i = tid; i < 4 * NROWS * HSTR; i += 256) hsu[i] = 0u;
  // Pack conv2 weights into LDS: 3 entries per thread.
  for (int t = tid; t < 768; t += 256) {
    int oc = t / 48, k32 = t % 48;
    unsigned v = 0u;
    if (k32 < 36) {
      int icp = k32 / 9, tap = k32 - icp * 9;
      v = pack_f16(w2[(oc * 8 + 2 * icp) * 9 + tap],
                   w2[(oc * 8 + 2 * icp + 1) * 9 + tap]);
    }
    bwl[t] = v;
  }
  // Pack patch weights: wps[i*4+ot] = f16pair over lanes (2i, 2i+1) for ot.
  if (tid < 128) {
    int i = tid >> 2, ot = tid & 3;
    int l0 = 2 * i, l1 = 2 * i + 1;
    wps[tid] = pack_f16(wp[ot * 64 + (l0 & 15) * 4 + (l0 >> 4)],
                        wp[ot * 64 + (l1 & 15) * 4 + (l1 >> 4)]);
  }
  __syncthreads();

  // ---- P1: conv1(1->8)+bias+relu+maxpool2 (packed f32) -> f16 LDS tile ----
  for (int task = tid; task < 1680; task += 256) {
    int r = task / 56, hc = task % 56;
    int gr = 28 * s - 1 + r;
    if ((unsigned)gr >= 56u) continue;
    float win[4][4];
    int iy0 = 2 * gr - 1, ix0 = 2 * hc - 1;
#pragma unroll
    for (int rr = 0; rr < 4; ++rr) {
      int iy = iy0 + rr;
      bool yok = (unsigned)iy < 112u;
#pragma unroll
      for (int qq = 0; qq < 4; ++qq) {
        int ix = ix0 + qq;
        win[rr][qq] = (yok && (unsigned)ix < 112u) ? xb[iy * 112 + ix] : 0.f;
      }
    }
    float hv[8];
#pragma unroll
    for (int c = 0; c < 8; ++c) {
      f32x2 sA = {0.f, 0.f};  // (s00, s01)
      f32x2 sB = {0.f, 0.f};  // (s10, s11)
#pragma unroll
      for (int ty = 0; ty < 3; ++ty)
#pragma unroll
        for (int tx = 0; tx < 3; ++tx) {
          float wk = w1[c * 9 + ty * 3 + tx];
          f32x2 wkk = {wk, wk};
          f32x2 xa = {win[ty][tx], win[ty][tx + 1]};
          f32x2 xb2 = {win[ty + 1][tx], win[ty + 1][tx + 1]};
          sA = __builtin_elementwise_fma(xa, wkk, sA);
          sB = __builtin_elementwise_fma(xb2, wkk, sB);
        }
      f32x2 sm = __builtin_elementwise_max(sA, sB);
      float m = fmaxf(sm.x, sm.y);
      hv[c] = fmaxf(m + b1[c], 0.f);
    }
#pragma unroll
    for (int cp = 0; cp < 4; ++cp)
      hsu[(cp * NROWS + r) * HSTR + 1 + hc] = pack_f16(hv[2 * cp], hv[2 * cp + 1]);
  }
  __syncthreads();

  // ---- P2: conv2+pool+relu via MFMA; fv -> fsu; chunked patch reduce ----
  {
    const int q = l >> 4;  // k-octet / fmem role
    int offs[12];
#pragma unroll
    for (int kk = 0; kk < 3; ++kk)
#pragma unroll
      for (int i = 0; i < 4; ++i) {
        int k32 = kk * 16 + q * 4 + i;
        int icp = k32 / 9, tap = k32 - icp * 9;
        int ty = tap / 3, tx = tap - ty * 3;
        offs[kk * 4 + i] = (icp * NROWS + ty) * HSTR + tx;  // junk if k32>=36
      }
    const int yoff = 2 * ((l >> 3) & 1) + ((l >> 1) & 1);  // 2a+dy
    const int xoff = 2 * ((l >> 2) & 1) + (l & 1);         // 2b+dx
    uint4 bu0 = *(const uint4*)(bwl + (l & 15) * 48 + 0 * 16 + q * 4);
    uint4 bu1 = *(const uint4*)(bwl + (l & 15) * 48 + 1 * 16 + q * 4);
    uint4 bu2 = *(const uint4*)(bwl + (l & 15) * 48 + 2 * 16 + q * 4);
    const float b2v = b2[l & 15];
    _Float16* fsh = (_Float16*)fsu;

#pragma unroll 1
    for (int c = 0; c < 2; ++c) {  // chunk: patches c*49 .. c*49+48
#pragma unroll 2
      for (int p_l = wv; p_l < 49; p_l += 4) {
        int p = c * 49 + p_l;
        int py = p / 14, px = p - py * 14;
        int base = (4 * py + yoff) * HSTR + 4 * px + xoff;
        uint4 a0u, a1u, a2u = make_uint4(0u, 0u, 0u, 0u);
        a0u.x = hsu[base + offs[0]];
        a0u.y = hsu[base + offs[1]];
        a0u.z = hsu[base + offs[2]];
        a0u.w = hsu[base + offs[3]];
        a1u.x = hsu[base + offs[4]];
        a1u.y = hsu[base + offs[5]];
        a1u.z = hsu[base + offs[6]];
        a1u.w = hsu[base + offs[7]];
        if (q == 0) {  // only k32 32..35 real in K-step 2
          a2u.x = hsu[base + offs[8]];
          a2u.y = hsu[base + offs[9]];
          a2u.z = hsu[base + offs[10]];
          a2u.w = hsu[base + offs[11]];
        }
        f32x4 acc = {0.f, 0.f, 0.f, 0.f};
        acc = __builtin_amdgcn_mfma_f32_16x16x32_f16(as_f16x8(a0u), as_f16x8(bu0), acc, 0, 0, 0);
        acc = __builtin_amdgcn_mfma_f32_16x16x32_f16(as_f16x8(a1u), as_f16x8(bu1), acc, 0, 0, 0);
        acc = __builtin_amdgcn_mfma_f32_16x16x32_f16(as_f16x8(a2u), as_f16x8(bu2), acc, 0, 0, 0);
        float mx = fmaxf(fmaxf(acc[0], acc[1]), fmaxf(acc[2], acc[3]));
        float fv = fmaxf(mx + b2v, 0.f);  // f[oc=l&15][f-pixel fmem=q of patch p]
        fsh[p_l * (2 * FSTR) + l] = (_Float16)fv;
      }
      __syncthreads();
      // chunk reduce: thread t<196 -> (row=p_l, ot); 32 fdot2 over 64 lanes
      if (tid < 196) {
        int row = tid >> 2, ot = tid & 3;
        int p = c * 49 + row;
        const unsigned* fr = fsu + row * FSTR;
        float acc = 0.f;
#pragma unroll
        for (int i = 0; i < 32; ++i)
          acc = fdot2_(as_h2(fr[i]), as_h2(wps[i * 4 + ot]), acc);
        pfl[p * 4 + ot] = acc + bpv;
      }
      __syncthreads();
    }
  }

  // ---- P3: fc1 partial over this tile's pf slice [392s, 392s+392) ----
  {
    int j = tid >> 2, q4 = tid & 3;
    const float2* wrow = (const float2*)(w_fc1 + j * 784 + 392 * s + q4 * 98);
    const float2* pv = (const float2*)(pfl + q4 * 98);
    float acc = 0.f;
#pragma unroll 7
    for (int m = 0; m < 49; ++m) {
      float2 wv2 = wrow[m], fv2 = pv[m];
      acc += wv2.x * fv2.x + wv2.y * fv2.y;
    }
    acc += __shfl_down(acc, 2, 4);
    acc += __shfl_down(acc, 1, 4);
    if (q4 == 0) h1p[((long)b * 2 + s) * 64 + j] = acc;
  }
}

// ---------------- k_tail: combine partials + fc2 + log_softmax --------------
__global__ __launch_bounds__(64) void k_tail(const float* __restrict__ h1p,
                                             const float* __restrict__ b_fc1,
                                             const float* __restrict__ w_fc2,
                                             const float* __restrict__ b_fc2,
                                             float* __restrict__ out) {
  __shared__ float h1s[64];
  __shared__ float red[11];
  int b = blockIdx.x, j = threadIdx.x;
  float v = b_fc1[j] + h1p[(long)b * 128 + j] + h1p[(long)b * 128 + 64 + j];
  h1s[j] = fmaxf(v, 0.f);
  __syncthreads();
  if (j < 10) {
    float acc = b_fc2[j];
    const float* wo = w_fc2 + j * 64;
#pragma unroll
    for (int k = 0; k < 64; ++k) acc += h1s[k] * wo[k];
    red[j] = acc;
  }
  __syncthreads();
  if (j == 0) {
    float mx = red[0];
    for (int o = 1; o < 10; ++o) mx = fmaxf(mx, red[o]);
    float se = 0.f;
    for (int o = 0; o < 10; ++o) se += expf(red[o] - mx);
    red[10] = mx + logf(se);
  }
  __syncthreads();
  if (j < 10) out[b * 10 + j] = red[j] - red[10];
}

extern "C" void kernel_launch(void* const* d_in, const int* in_sizes, int n_in,
                              void* d_out, int out_size, void* d_ws, size_t ws_size,
                              hipStream_t stream) {
  const float* x = (const float*)d_in[0];
  const float* w1 = (const float*)d_in[1];
  const float* b1 = (const float*)d_in[2];
  const float* w2 = (const float*)d_in[3];
  const float* b2 = (const float*)d_in[4];
  const float* wp = (const float*)d_in[5];
  const float* bp = (const float*)d_in[6];
  const float* wf1 = (const float*)d_in[7];
  const float* bf1 = (const float*)d_in[8];
  const float* wf2 = (const float*)d_in[9];
  const float* bf2 = (const float*)d_in[10];

  float* h1p = (float*)d_ws;  // [512][2][64] = 65536 floats (256 KB)

  k_fused<<<dim3(1024), 256, 0, stream>>>(x, w1, b1, w2, b2, wp, bp, wf1, h1p);
  k_tail<<<dim3(512), 64, 0, stream>>>(h1p, bf1, wf2, bf2, (float*)d_out);
}